// Round 6
// baseline (27038.785 us; speedup 1.0000x reference)
//
#include <hip/hip_runtime.h>
#include <cstdint>
#include <cstddef>

#define NB    32     // batch
#define NTT   2048   // time steps
#define NIN   256    // input size
#define NH    256    // hidden
#define NG    16     // workgroups
#define BLOCK 512    // threads per WG (8 waves)
#define NHC   16     // h-cols per WG (z-cols = 64)

typedef __attribute__((ext_vector_type(8))) short    s8v;
typedef __attribute__((ext_vector_type(4))) float    f4v;
typedef __attribute__((ext_vector_type(4))) unsigned u4v;
typedef __attribute__((ext_vector_type(2))) unsigned u2v;

__device__ __forceinline__ float u2f(unsigned u) {
    union { float f; unsigned u; } x; x.u = u; return x.f;
}
__device__ __forceinline__ unsigned cvt_pk_bf16(float s0, float s1) {
    unsigned r;
    asm("v_cvt_pk_bf16_f32 %0, %1, %2" : "=v"(r) : "v"(s0), "v"(s1));
    return r;  // lo16 = bf16(s0), hi16 = bf16(s1)
}
__device__ __forceinline__ void split2(float v0, float v1, unsigned& hp, unsigned& lp) {
    hp = cvt_pk_bf16(v0, v1);
    float h0 = u2f(hp << 16);
    float h1 = u2f(hp & 0xFFFF0000u);
    lp = cvt_pk_bf16(v0 - h0, v1 - h1);  // lo compensates hi rounding exactly in fp32
}
__device__ __forceinline__ void split8(f4v a, f4v b, u4v& hw, u4v& lw) {
    unsigned h0,h1,h2,h3,l0,l1,l2,l3;
    split2(a[0], a[1], h0, l0);
    split2(a[2], a[3], h1, l1);
    split2(b[0], b[1], h2, l2);
    split2(b[2], b[3], h3, l3);
    hw = (u4v){h0,h1,h2,h3};
    lw = (u4v){l0,l1,l2,l3};
}
__device__ __forceinline__ float fast_sig(float v) {
    const float L2E = 1.4426950408889634f;
    return __builtin_amdgcn_rcpf(1.f + __builtin_amdgcn_exp2f(-L2E * v));
}
__device__ __forceinline__ float fast_tanh(float v) {
    const float L2E2 = 2.8853900817779268f;
    float e = __builtin_amdgcn_exp2f(L2E2 * v);
    return 1.f - 2.f * __builtin_amdgcn_rcpf(e + 1.f);
}

// ---- device-scope (sc1 = MALL coherence point) tagged-atom ops ----
// 8 consecutive 8B atoms, each (payload, tag), "+v" so prior reg contents stay
// live (tag-check of un-landed loads then reads the PREVIOUS step's tag).
template<int OFF>
__device__ __forceinline__ void ld_atoms8(const unsigned long long* base,
        u2v& a0, u2v& a1, u2v& a2, u2v& a3, u2v& a4, u2v& a5, u2v& a6, u2v& a7) {
    asm volatile(
        "global_load_dwordx2 %0, %8, off offset:%c9  sc1\n\t"
        "global_load_dwordx2 %1, %8, off offset:%c10 sc1\n\t"
        "global_load_dwordx2 %2, %8, off offset:%c11 sc1\n\t"
        "global_load_dwordx2 %3, %8, off offset:%c12 sc1\n\t"
        "global_load_dwordx2 %4, %8, off offset:%c13 sc1\n\t"
        "global_load_dwordx2 %5, %8, off offset:%c14 sc1\n\t"
        "global_load_dwordx2 %6, %8, off offset:%c15 sc1\n\t"
        "global_load_dwordx2 %7, %8, off offset:%c16 sc1"
        : "+v"(a0), "+v"(a1), "+v"(a2), "+v"(a3),
          "+v"(a4), "+v"(a5), "+v"(a6), "+v"(a7)
        : "v"(base), "n"(OFF), "n"(OFF+8), "n"(OFF+16), "n"(OFF+24),
          "n"(OFF+32), "n"(OFF+40), "n"(OFF+48), "n"(OFF+56)
        : "memory");
}
__device__ __forceinline__ void st_atom(unsigned long long* p, unsigned payload, unsigned tag) {
    u2v v; v[0] = payload; v[1] = tag;
    asm volatile("global_store_dwordx2 %0, %1, off sc1" :: "v"(p), "v"(v) : "memory");
}
// plain x prefetch: 2 x dwordx4
template<int OFF>
__device__ __forceinline__ void pf_ld4x2(const float* base, f4v& a, f4v& b) {
    asm volatile(
        "global_load_dwordx4 %0, %2, off offset:%c3\n\t"
        "global_load_dwordx4 %1, %2, off offset:%c4"
        : "=&v"(a), "=&v"(b)
        : "v"(base), "n"(OFF), "n"(OFF+16)
        : "memory");
}

// A LDS tile: [32 rows][512 bf16] hi/lo planes; 16B-chunk XOR swizzle:
// chunk kc (0..63) of row r lives at byte r*1024 + ((kc ^ (r&7)) << 4).
// Chunks 0..31 = x-part (k 0..255), 32..63 = h-part (k 256..511).

__global__ __launch_bounds__(BLOCK, 1) void lstm_kernel(
    const float* __restrict__ x,
    const float* __restrict__ Wf, const float* __restrict__ bfp,
    const float* __restrict__ Wi, const float* __restrict__ bip,
    const float* __restrict__ Wo, const float* __restrict__ bop,
    const float* __restrict__ Wc, const float* __restrict__ bcp,
    float* __restrict__ out,
    unsigned long long* __restrict__ hatoms)   // [2][32][256] atoms (payload, tag)
{
    __shared__ unsigned short Ahi[NB * 512];
    __shared__ unsigned short Alo[NB * 512];
    __shared__ float zbuf[32][68];     // 64 z-cols + pad

    char* AhiB = (char*)Ahi;
    char* AloB = (char*)Alo;
    const int wg   = blockIdx.x;
    const int tid  = threadIdx.x;
    const int lane = tid & 63;
    const int wv   = tid >> 6;
    const int mt   = wv & 1;   // M-tile (batch rows mt*16..)
    const int nt   = wv >> 1;  // N-tile 0..3 (16 z-cols each; col group = gate nt)

    // ---------- weights: 2 passes through LDS -> persistent register B-frags ----------
    s8v bhi[16], blo[16];
    for (int p = 0; p < 2; ++p) {
        {
            const int lc   = tid >> 4;             // pass-local z-col 0..31
            const int gate = 2 * p + (lc >> 4);
            const int col  = wg * NHC + (lc & 15);
            const float* W = (gate == 0) ? Wf : (gate == 1) ? Wi : (gate == 2) ? Wo : Wc;
            #pragma unroll
            for (int cj = 0; cj < 4; ++cj) {
                const int kc = (tid & 15) * 4 + cj;
                const int k0 = kc * 8;
                f4v a, b;
                #pragma unroll
                for (int e = 0; e < 4; ++e) a[e] = W[(size_t)(k0 + e) * NH + col];
                #pragma unroll
                for (int e = 0; e < 4; ++e) b[e] = W[(size_t)(k0 + 4 + e) * NH + col];
                u4v hwv, lwv;
                split8(a, b, hwv, lwv);
                *(u4v*)(AhiB + lc * 1024 + ((kc ^ (lc & 7)) << 4)) = hwv;
                *(u4v*)(AloB + lc * 1024 + ((kc ^ (lc & 7)) << 4)) = lwv;
            }
        }
        __syncthreads();
        if ((nt >> 1) == p) {
            const int brow = (nt & 1) * 16 + (lane & 15);
            const int bsub = lane >> 4;
            #pragma unroll
            for (int kt = 0; kt < 16; ++kt) {
                const int kc = kt * 4 + bsub;
                bhi[kt] = *(s8v*)(AhiB + brow * 1024 + ((kc ^ (brow & 7)) << 4));
                blo[kt] = *(s8v*)(AloB + brow * 1024 + ((kc ^ (brow & 7)) << 4));
            }
        }
        __syncthreads();
    }

    // update role: thread = (batch ub, local h-col ulh)
    const int ub   = tid >> 4;
    const int ulh  = tid & 15;
    const int ucol = wg * NHC + ulh;
    const float bias_f = bfp[ucol];
    const float bias_i = bip[ucol];
    const float bias_o = bop[ucol];
    const float bias_c = bcp[ucol];
    float cst = 0.f;

    // staging role: thread = (row sb, segment sseg); handles chunks sseg*2+{0,1}
    const int sb   = tid >> 4;
    const int sseg = tid & 15;

    const int arow = mt * 16 + (lane & 15);
    const int asub = lane >> 4;

    // h atoms for this thread's staging slice (16 atoms = cols sseg*16..+15 of row sb)
    u2v hr[16];
    #pragma unroll
    for (int e = 0; e < 16; ++e) { hr[e][0] = 0u; hr[e][1] = 0u; }

    // prologue: x(0) plain loads, force-materialized BEFORE the loop so the
    // compiler's auto-waitcnt lands here, not inside the loop body.
    f4v xv[4];
    {
        const float* xr = x + (size_t)sb * NTT * NIN + sseg * 16;
        xv[0] = *(const f4v*)(xr);
        xv[1] = *(const f4v*)(xr + 4);
        xv[2] = *(const f4v*)(xr + 8);
        xv[3] = *(const f4v*)(xr + 12);
    }
    asm volatile("" : "+v"(xv[0]), "+v"(xv[1]), "+v"(xv[2]), "+v"(xv[3]));

    for (int t = 0; t < NTT; ++t) {
        // ---- S2: stage x-part (xv valid: prologue for t=0, E(t-1)'s vmcnt(0) after)
        #pragma unroll
        for (int j = 0; j < 2; ++j) {
            u4v hwv, lwv;
            split8(xv[2 * j], xv[2 * j + 1], hwv, lwv);
            const int kc = sseg * 2 + j;
            *(u4v*)(AhiB + sb * 1024 + ((kc ^ (sb & 7)) << 4)) = hwv;
            *(u4v*)(AloB + sb * 1024 + ((kc ^ (sb & 7)) << 4)) = lwv;
        }
        // ---- S3: issue x prefetch for t+1 (drained by this iteration's E-wait)
        {
            const int tp = (t < NTT - 1) ? t + 1 : t;
            const float* xr = x + ((size_t)sb * NTT + tp) * NIN + sseg * 16;
            pf_ld4x2<0>(xr, xv[0], xv[1]);
            pf_ld4x2<32>(xr, xv[2], xv[3]);
        }
        __syncthreads();   // B1: x-part staged

        // ---- MFMA x-part (k 0..255) — covers h-atom load latency
        f4v acc0 = (f4v){0.f, 0.f, 0.f, 0.f};
        f4v acc1 = acc0, acc2 = acc0;
        #pragma unroll
        for (int kt = 0; kt < 8; ++kt) {
            const int kc = kt * 4 + asub;
            s8v ah = *(s8v*)(AhiB + arow * 1024 + ((kc ^ (arow & 7)) << 4));
            s8v al = *(s8v*)(AloB + arow * 1024 + ((kc ^ (arow & 7)) << 4));
            acc0 = __builtin_amdgcn_mfma_f32_16x16x32_bf16(ah, bhi[kt], acc0, 0, 0, 0);
            acc1 = __builtin_amdgcn_mfma_f32_16x16x32_bf16(ah, blo[kt], acc1, 0, 0, 0);
            acc2 = __builtin_amdgcn_mfma_f32_16x16x32_bf16(al, bhi[kt], acc2, 0, 0, 0);
        }

        // ---- E: single wait; tags self-validate (un-landed regs hold tag t-1 != t)
        asm volatile("s_waitcnt vmcnt(0)" ::: "memory");
        __builtin_amdgcn_sched_barrier(0);
        if (t > 0) {
            const unsigned texp = (unsigned)t;
            unsigned d = 0;
            #pragma unroll
            for (int e = 0; e < 16; ++e) d |= (hr[e][1] ^ texp);
            int guard = 0;
            while (__any(d != 0)) {                 // stale -> re-load (self-paced ~1 RT)
                if (++guard > 8192) break;          // fail loud, never hang
                const unsigned long long* hp =
                    hatoms + (size_t)(t & 1) * (NB * NH) + (size_t)sb * NH + sseg * 16;
                ld_atoms8<0>(hp, hr[0], hr[1], hr[2], hr[3], hr[4], hr[5], hr[6], hr[7]);
                ld_atoms8<64>(hp, hr[8], hr[9], hr[10], hr[11], hr[12], hr[13], hr[14], hr[15]);
                asm volatile("s_waitcnt vmcnt(0)" ::: "memory");
                __builtin_amdgcn_sched_barrier(0);
                d = 0;
                #pragma unroll
                for (int e = 0; e < 16; ++e) d |= (hr[e][1] ^ texp);
            }
            // unpack payloads (hi | lo<<16) into hi/lo LDS chunks
            #pragma unroll
            for (int j = 0; j < 2; ++j) {
                const int b0 = j * 8;
                u4v hwv, lwv;
                hwv[0] = __builtin_amdgcn_perm(hr[b0+1][0], hr[b0+0][0], 0x05040100u);
                hwv[1] = __builtin_amdgcn_perm(hr[b0+3][0], hr[b0+2][0], 0x05040100u);
                hwv[2] = __builtin_amdgcn_perm(hr[b0+5][0], hr[b0+4][0], 0x05040100u);
                hwv[3] = __builtin_amdgcn_perm(hr[b0+7][0], hr[b0+6][0], 0x05040100u);
                lwv[0] = __builtin_amdgcn_perm(hr[b0+1][0], hr[b0+0][0], 0x07060302u);
                lwv[1] = __builtin_amdgcn_perm(hr[b0+3][0], hr[b0+2][0], 0x07060302u);
                lwv[2] = __builtin_amdgcn_perm(hr[b0+5][0], hr[b0+4][0], 0x07060302u);
                lwv[3] = __builtin_amdgcn_perm(hr[b0+7][0], hr[b0+6][0], 0x07060302u);
                const int kc = 32 + sseg * 2 + j;
                *(u4v*)(AhiB + sb * 1024 + ((kc ^ (sb & 7)) << 4)) = hwv;
                *(u4v*)(AloB + sb * 1024 + ((kc ^ (sb & 7)) << 4)) = lwv;
            }
        } else {
            const u4v zz = (u4v){0u, 0u, 0u, 0u};
            #pragma unroll
            for (int j = 0; j < 2; ++j) {
                const int kc = 32 + sseg * 2 + j;
                *(u4v*)(AhiB + sb * 1024 + ((kc ^ (sb & 7)) << 4)) = zz;
                *(u4v*)(AloB + sb * 1024 + ((kc ^ (sb & 7)) << 4)) = zz;
            }
        }
        __syncthreads();   // B3: h-part staged

        // ---- MFMA h-part (k 256..511)
        #pragma unroll
        for (int kt = 8; kt < 16; ++kt) {
            const int kc = kt * 4 + asub;
            s8v ah = *(s8v*)(AhiB + arow * 1024 + ((kc ^ (arow & 7)) << 4));
            s8v al = *(s8v*)(AloB + arow * 1024 + ((kc ^ (arow & 7)) << 4));
            acc0 = __builtin_amdgcn_mfma_f32_16x16x32_bf16(ah, bhi[kt], acc0, 0, 0, 0);
            acc1 = __builtin_amdgcn_mfma_f32_16x16x32_bf16(ah, blo[kt], acc1, 0, 0, 0);
            acc2 = __builtin_amdgcn_mfma_f32_16x16x32_bf16(al, bhi[kt], acc2, 0, 0, 0);
        }
        const f4v zv = acc0 + acc1 + acc2;

        // ---- G: z exchange; C layout: col=l&15, row=(l>>4)*4+j
        {
            const int zc = nt * 16 + (lane & 15);
            const int rb = mt * 16 + (lane >> 4) * 4;
            #pragma unroll
            for (int j = 0; j < 4; ++j)
                zbuf[rb + j][zc] = zv[j];
        }
        __syncthreads();   // B5: z visible

        // ---- H: gates + state update + tagged publish + speculative next-step loads
        {
            const float zf = zbuf[ub][ulh]      + bias_f;
            const float zi = zbuf[ub][16 + ulh] + bias_i;
            const float zo = zbuf[ub][32 + ulh] + bias_o;
            const float zg = zbuf[ub][48 + ulh] + bias_c;
            const float fg = fast_sig(zf);
            const float ig = fast_sig(zi);
            const float og = fast_sig(zo);
            const float gg = fast_tanh(zg);
            cst = fg * cst + ig * gg;
            const float hv = og * fast_tanh(cst);
            // pack hi|lo<<16, publish (payload, tag=t+1) as one 8B atom
            unsigned p0  = cvt_pk_bf16(hv, 0.f);
            float   hif  = u2f(p0 << 16);
            unsigned w   = cvt_pk_bf16(hv, hv - hif);
            st_atom(hatoms + (size_t)((t + 1) & 1) * (NB * NH) + (size_t)ub * NH + ucol,
                    w, (unsigned)(t + 1));
            // output is reverse-time order; plain cached store (non-blocking)
            out[((size_t)ub * NTT + (NTT - 1 - t)) * NH + ucol] = hv;
        }
        if (t < NTT - 1) {
            const unsigned long long* hp =
                hatoms + (size_t)((t + 1) & 1) * (NB * NH) + (size_t)sb * NH + sseg * 16;
            ld_atoms8<0>(hp, hr[0], hr[1], hr[2], hr[3], hr[4], hr[5], hr[6], hr[7]);
            ld_atoms8<64>(hp, hr[8], hr[9], hr[10], hr[11], hr[12], hr[13], hr[14], hr[15]);
        }
        // no end-of-step barrier, no flag, no ack: next E's vmcnt(0) + tags do it all
    }
}

extern "C" void kernel_launch(void* const* d_in, const int* in_sizes, int n_in,
                              void* d_out, int out_size, void* d_ws, size_t ws_size,
                              hipStream_t stream) {
    (void)in_sizes; (void)n_in; (void)out_size; (void)ws_size;
    const float* x  = (const float*)d_in[0];
    const float* Wf = (const float*)d_in[1];
    const float* bf = (const float*)d_in[2];
    const float* Wi = (const float*)d_in[3];
    const float* bi = (const float*)d_in[4];
    const float* Wo = (const float*)d_in[5];
    const float* bo = (const float*)d_in[6];
    const float* Wc = (const float*)d_in[7];
    const float* bc = (const float*)d_in[8];
    float* out = (float*)d_out;

    // [2][32][256] 8B atoms = 128 KiB; harness poison 0xAAAAAAAA is never a
    // valid tag (tags are 1..2048), so no memset is needed.
    unsigned long long* hatoms = (unsigned long long*)d_ws;

    lstm_kernel<<<NG, BLOCK, 0, stream>>>(x, Wf, bf, Wi, bi, Wo, bo, Wc, bc,
                                          out, hatoms);
}

// Round 7
// 19008.234 us; speedup vs baseline: 1.4225x; 1.4225x over previous
//
#include <hip/hip_runtime.h>
#include <cstdint>
#include <cstddef>

#define NB    32     // batch
#define NTT   2048   // time steps
#define NIN   256    // input size
#define NH    256    // hidden
#define NG    16     // workgroups
#define BLOCK 512    // threads per WG (8 waves)
#define NHC   16     // h-cols per WG (z-cols = 64)

typedef __attribute__((ext_vector_type(8))) short    s8v;
typedef __attribute__((ext_vector_type(4))) float    f4v;
typedef __attribute__((ext_vector_type(4))) unsigned u4v;
typedef __attribute__((ext_vector_type(2))) unsigned u2v;

__device__ __forceinline__ float u2f(unsigned u) {
    union { float f; unsigned u; } x; x.u = u; return x.f;
}
__device__ __forceinline__ unsigned cvt_pk_bf16(float s0, float s1) {
    unsigned r;
    asm("v_cvt_pk_bf16_f32 %0, %1, %2" : "=v"(r) : "v"(s0), "v"(s1));
    return r;  // lo16 = bf16(s0), hi16 = bf16(s1)
}
__device__ __forceinline__ void split2(float v0, float v1, unsigned& hp, unsigned& lp) {
    hp = cvt_pk_bf16(v0, v1);
    float h0 = u2f(hp << 16);
    float h1 = u2f(hp & 0xFFFF0000u);
    lp = cvt_pk_bf16(v0 - h0, v1 - h1);  // lo compensates hi rounding exactly in fp32
}
__device__ __forceinline__ void split8(f4v a, f4v b, u4v& hw, u4v& lw) {
    unsigned h0,h1,h2,h3,l0,l1,l2,l3;
    split2(a[0], a[1], h0, l0);
    split2(a[2], a[3], h1, l1);
    split2(b[0], b[1], h2, l2);
    split2(b[2], b[3], h3, l3);
    hw = (u4v){h0,h1,h2,h3};
    lw = (u4v){l0,l1,l2,l3};
}
__device__ __forceinline__ float fast_sig(float v) {
    const float L2E = 1.4426950408889634f;
    return __builtin_amdgcn_rcpf(1.f + __builtin_amdgcn_exp2f(-L2E * v));
}
__device__ __forceinline__ float fast_tanh(float v) {
    const float L2E2 = 2.8853900817779268f;
    float e = __builtin_amdgcn_exp2f(L2E2 * v);
    return 1.f - 2.f * __builtin_amdgcn_rcpf(e + 1.f);
}

// ---- device-scope (sc1 = MALL coherence point) tagged-atom ops ----
// 8 consecutive 8B atoms, each (payload, tag); naturally-aligned 64b accesses
// are single-copy atomic, so tag==t guarantees payload validity in-atom.
template<int OFF>
__device__ __forceinline__ void ld_atoms8(const unsigned long long* base,
        u2v& a0, u2v& a1, u2v& a2, u2v& a3, u2v& a4, u2v& a5, u2v& a6, u2v& a7) {
    asm volatile(
        "global_load_dwordx2 %0, %8, off offset:%c9  sc1\n\t"
        "global_load_dwordx2 %1, %8, off offset:%c10 sc1\n\t"
        "global_load_dwordx2 %2, %8, off offset:%c11 sc1\n\t"
        "global_load_dwordx2 %3, %8, off offset:%c12 sc1\n\t"
        "global_load_dwordx2 %4, %8, off offset:%c13 sc1\n\t"
        "global_load_dwordx2 %5, %8, off offset:%c14 sc1\n\t"
        "global_load_dwordx2 %6, %8, off offset:%c15 sc1\n\t"
        "global_load_dwordx2 %7, %8, off offset:%c16 sc1"
        : "+v"(a0), "+v"(a1), "+v"(a2), "+v"(a3),
          "+v"(a4), "+v"(a5), "+v"(a6), "+v"(a7)
        : "v"(base), "n"(OFF), "n"(OFF+8), "n"(OFF+16), "n"(OFF+24),
          "n"(OFF+32), "n"(OFF+40), "n"(OFF+48), "n"(OFF+56)
        : "memory");
}
__device__ __forceinline__ void st_atom(unsigned long long* p, unsigned payload, unsigned tag) {
    u2v v; v[0] = payload; v[1] = tag;
    asm volatile("global_store_dwordx2 %0, %1, off sc1" :: "v"(p), "v"(v) : "memory");
}
// plain x prefetch: 2 x dwordx4
template<int OFF>
__device__ __forceinline__ void pf_ld4x2(const float* base, f4v& a, f4v& b) {
    asm volatile(
        "global_load_dwordx4 %0, %2, off offset:%c3\n\t"
        "global_load_dwordx4 %1, %2, off offset:%c4"
        : "=&v"(a), "=&v"(b)
        : "v"(base), "n"(OFF), "n"(OFF+16)
        : "memory");
}

// A LDS tile: [32 rows][512 bf16] hi/lo planes; 16B-chunk XOR swizzle:
// chunk kc (0..63) of row r lives at byte r*1024 + ((kc ^ (r&7)) << 4).
// Chunks 0..31 = x-part (k 0..255), 32..63 = h-part (k 256..511).

__global__ __launch_bounds__(BLOCK, 1) void lstm_kernel(
    const float* __restrict__ x,
    const float* __restrict__ Wf, const float* __restrict__ bfp,
    const float* __restrict__ Wi, const float* __restrict__ bip,
    const float* __restrict__ Wo, const float* __restrict__ bop,
    const float* __restrict__ Wc, const float* __restrict__ bcp,
    float* __restrict__ out,
    unsigned long long* __restrict__ hatoms)   // [2][32][256] atoms (payload, tag)
{
    __shared__ unsigned short Ahi[NB * 512];
    __shared__ unsigned short Alo[NB * 512];
    __shared__ float zbuf[32][68];     // 64 z-cols + pad

    char* AhiB = (char*)Ahi;
    char* AloB = (char*)Alo;
    const int wg   = blockIdx.x;
    const int tid  = threadIdx.x;
    const int lane = tid & 63;
    const int wv   = tid >> 6;
    const int mt   = wv & 1;   // M-tile (batch rows mt*16..)
    const int nt   = wv >> 1;  // N-tile 0..3 (16 z-cols each; col group = gate nt)

    // ---------- weights: 2 passes through LDS -> persistent register B-frags ----------
    s8v bhi[16], blo[16];
    for (int p = 0; p < 2; ++p) {
        {
            const int lc   = tid >> 4;             // pass-local z-col 0..31
            const int gate = 2 * p + (lc >> 4);
            const int col  = wg * NHC + (lc & 15);
            const float* W = (gate == 0) ? Wf : (gate == 1) ? Wi : (gate == 2) ? Wo : Wc;
            #pragma unroll
            for (int cj = 0; cj < 4; ++cj) {
                const int kc = (tid & 15) * 4 + cj;
                const int k0 = kc * 8;
                f4v a, b;
                #pragma unroll
                for (int e = 0; e < 4; ++e) a[e] = W[(size_t)(k0 + e) * NH + col];
                #pragma unroll
                for (int e = 0; e < 4; ++e) b[e] = W[(size_t)(k0 + 4 + e) * NH + col];
                u4v hwv, lwv;
                split8(a, b, hwv, lwv);
                *(u4v*)(AhiB + lc * 1024 + ((kc ^ (lc & 7)) << 4)) = hwv;
                *(u4v*)(AloB + lc * 1024 + ((kc ^ (lc & 7)) << 4)) = lwv;
            }
        }
        __syncthreads();
        if ((nt >> 1) == p) {
            const int brow = (nt & 1) * 16 + (lane & 15);
            const int bsub = lane >> 4;
            #pragma unroll
            for (int kt = 0; kt < 16; ++kt) {
                const int kc = kt * 4 + bsub;
                bhi[kt] = *(s8v*)(AhiB + brow * 1024 + ((kc ^ (brow & 7)) << 4));
                blo[kt] = *(s8v*)(AloB + brow * 1024 + ((kc ^ (brow & 7)) << 4));
            }
        }
        __syncthreads();
    }

    // update role: thread = (batch ub, local h-col ulh)
    const int ub   = tid >> 4;
    const int ulh  = tid & 15;
    const int ucol = wg * NHC + ulh;
    const float bias_f = bfp[ucol];
    const float bias_i = bip[ucol];
    const float bias_o = bop[ucol];
    const float bias_c = bcp[ucol];
    float cst = 0.f;

    // staging role: thread = (row sb, segment sseg); handles chunks sseg*2+{0,1}
    const int sb   = tid >> 4;
    const int sseg = tid & 15;

    const int arow = mt * 16 + (lane & 15);
    const int asub = lane >> 4;

    // h atoms for this thread's staging slice (16 atoms = cols sseg*16..+15 of row sb)
    u2v hr[16];
    #pragma unroll
    for (int e = 0; e < 16; ++e) { hr[e][0] = 0u; hr[e][1] = 0u; }

    // prologue: x(0) plain loads, force-materialized before the loop
    f4v xv[4];
    {
        const float* xr = x + (size_t)sb * NTT * NIN + sseg * 16;
        xv[0] = *(const f4v*)(xr);
        xv[1] = *(const f4v*)(xr + 4);
        xv[2] = *(const f4v*)(xr + 8);
        xv[3] = *(const f4v*)(xr + 12);
    }
    asm volatile("" : "+v"(xv[0]), "+v"(xv[1]), "+v"(xv[2]), "+v"(xv[3]));

    for (int t = 0; t < NTT; ++t) {
        // ---- S2: stage x-part (xv valid: prologue for t=0, E(t-1)'s vmcnt(0) after)
        #pragma unroll
        for (int j = 0; j < 2; ++j) {
            u4v hwv, lwv;
            split8(xv[2 * j], xv[2 * j + 1], hwv, lwv);
            const int kc = sseg * 2 + j;
            *(u4v*)(AhiB + sb * 1024 + ((kc ^ (sb & 7)) << 4)) = hwv;
            *(u4v*)(AloB + sb * 1024 + ((kc ^ (sb & 7)) << 4)) = lwv;
        }
        // ---- S3: issue x prefetch for t+1 (drained by this iteration's E-wait)
        {
            const int tp = (t < NTT - 1) ? t + 1 : t;
            const float* xr = x + ((size_t)sb * NTT + tp) * NIN + sseg * 16;
            pf_ld4x2<0>(xr, xv[0], xv[1]);
            pf_ld4x2<32>(xr, xv[2], xv[3]);
        }
        __syncthreads();   // B1: x-part staged

        // ---- MFMA x-part (k 0..255) — runs while producers' stores are in flight
        f4v acc0 = (f4v){0.f, 0.f, 0.f, 0.f};
        f4v acc1 = acc0, acc2 = acc0;
        #pragma unroll
        for (int kt = 0; kt < 8; ++kt) {
            const int kc = kt * 4 + asub;
            s8v ah = *(s8v*)(AhiB + arow * 1024 + ((kc ^ (arow & 7)) << 4));
            s8v al = *(s8v*)(AloB + arow * 1024 + ((kc ^ (arow & 7)) << 4));
            acc0 = __builtin_amdgcn_mfma_f32_16x16x32_bf16(ah, bhi[kt], acc0, 0, 0, 0);
            acc1 = __builtin_amdgcn_mfma_f32_16x16x32_bf16(ah, blo[kt], acc1, 0, 0, 0);
            acc2 = __builtin_amdgcn_mfma_f32_16x16x32_bf16(al, bhi[kt], acc2, 0, 0, 0);
        }

        // ---- E: LATE-issued tagged h loads; one wait; retry with backoff if stale
        const unsigned long long* hp =
            hatoms + (size_t)(t & 1) * (NB * NH) + (size_t)sb * NH + sseg * 16;
        if (t > 0) {
            ld_atoms8<0>(hp, hr[0], hr[1], hr[2], hr[3], hr[4], hr[5], hr[6], hr[7]);
            ld_atoms8<64>(hp, hr[8], hr[9], hr[10], hr[11], hr[12], hr[13], hr[14], hr[15]);
        }
        asm volatile("s_waitcnt vmcnt(0)" ::: "memory");   // h loads + x prefetch drained
        __builtin_amdgcn_sched_barrier(0);
        if (t > 0) {
            const unsigned texp = (unsigned)t;
            unsigned d = 0;
            #pragma unroll
            for (int e = 0; e < 16; ++e) d |= (hr[e][1] ^ texp);
            int guard = 0;
            while (__any(d != 0)) {                 // stale -> backoff, re-load
                if (++guard > (1 << 14)) break;     // fail loud, never hang
                __builtin_amdgcn_s_sleep(1);
                ld_atoms8<0>(hp, hr[0], hr[1], hr[2], hr[3], hr[4], hr[5], hr[6], hr[7]);
                ld_atoms8<64>(hp, hr[8], hr[9], hr[10], hr[11], hr[12], hr[13], hr[14], hr[15]);
                asm volatile("s_waitcnt vmcnt(0)" ::: "memory");
                __builtin_amdgcn_sched_barrier(0);
                d = 0;
                #pragma unroll
                for (int e = 0; e < 16; ++e) d |= (hr[e][1] ^ texp);
            }
            // unpack payloads (hi | lo<<16) into hi/lo LDS chunks
            #pragma unroll
            for (int j = 0; j < 2; ++j) {
                const int b0 = j * 8;
                u4v hwv, lwv;
                hwv[0] = __builtin_amdgcn_perm(hr[b0+1][0], hr[b0+0][0], 0x05040100u);
                hwv[1] = __builtin_amdgcn_perm(hr[b0+3][0], hr[b0+2][0], 0x05040100u);
                hwv[2] = __builtin_amdgcn_perm(hr[b0+5][0], hr[b0+4][0], 0x05040100u);
                hwv[3] = __builtin_amdgcn_perm(hr[b0+7][0], hr[b0+6][0], 0x05040100u);
                lwv[0] = __builtin_amdgcn_perm(hr[b0+1][0], hr[b0+0][0], 0x07060302u);
                lwv[1] = __builtin_amdgcn_perm(hr[b0+3][0], hr[b0+2][0], 0x07060302u);
                lwv[2] = __builtin_amdgcn_perm(hr[b0+5][0], hr[b0+4][0], 0x07060302u);
                lwv[3] = __builtin_amdgcn_perm(hr[b0+7][0], hr[b0+6][0], 0x07060302u);
                const int kc = 32 + sseg * 2 + j;
                *(u4v*)(AhiB + sb * 1024 + ((kc ^ (sb & 7)) << 4)) = hwv;
                *(u4v*)(AloB + sb * 1024 + ((kc ^ (sb & 7)) << 4)) = lwv;
            }
        } else {
            const u4v zz = (u4v){0u, 0u, 0u, 0u};
            #pragma unroll
            for (int j = 0; j < 2; ++j) {
                const int kc = 32 + sseg * 2 + j;
                *(u4v*)(AhiB + sb * 1024 + ((kc ^ (sb & 7)) << 4)) = zz;
                *(u4v*)(AloB + sb * 1024 + ((kc ^ (sb & 7)) << 4)) = zz;
            }
        }
        __syncthreads();   // B3: h-part staged

        // ---- MFMA h-part (k 256..511)
        #pragma unroll
        for (int kt = 8; kt < 16; ++kt) {
            const int kc = kt * 4 + asub;
            s8v ah = *(s8v*)(AhiB + arow * 1024 + ((kc ^ (arow & 7)) << 4));
            s8v al = *(s8v*)(AloB + arow * 1024 + ((kc ^ (arow & 7)) << 4));
            acc0 = __builtin_amdgcn_mfma_f32_16x16x32_bf16(ah, bhi[kt], acc0, 0, 0, 0);
            acc1 = __builtin_amdgcn_mfma_f32_16x16x32_bf16(ah, blo[kt], acc1, 0, 0, 0);
            acc2 = __builtin_amdgcn_mfma_f32_16x16x32_bf16(al, bhi[kt], acc2, 0, 0, 0);
        }
        const f4v zv = acc0 + acc1 + acc2;

        // ---- G: z exchange; C layout: col=l&15, row=(l>>4)*4+j
        {
            const int zc = nt * 16 + (lane & 15);
            const int rb = mt * 16 + (lane >> 4) * 4;
            #pragma unroll
            for (int j = 0; j < 4; ++j)
                zbuf[rb + j][zc] = zv[j];
        }
        __syncthreads();   // B5: z visible

        // ---- H: gates + state update + tagged publish (no ack, no flag, no barrier)
        {
            const float zf = zbuf[ub][ulh]      + bias_f;
            const float zi = zbuf[ub][16 + ulh] + bias_i;
            const float zo = zbuf[ub][32 + ulh] + bias_o;
            const float zg = zbuf[ub][48 + ulh] + bias_c;
            const float fg = fast_sig(zf);
            const float ig = fast_sig(zi);
            const float og = fast_sig(zo);
            const float gg = fast_tanh(zg);
            cst = fg * cst + ig * gg;
            const float hv = og * fast_tanh(cst);
            // pack hi|lo<<16, publish (payload, tag=t+1) as one 8B atom
            unsigned p0  = cvt_pk_bf16(hv, 0.f);
            float   hif  = u2f(p0 << 16);
            unsigned w   = cvt_pk_bf16(hv, hv - hif);
            st_atom(hatoms + (size_t)((t + 1) & 1) * (NB * NH) + (size_t)ub * NH + ucol,
                    w, (unsigned)(t + 1));
            // output is reverse-time order; plain cached store (non-blocking)
            out[((size_t)ub * NTT + (NTT - 1 - t)) * NH + ucol] = hv;
        }
        // loop back: S2 uses xv (drained at this step's E-wait); next E-wait
        // drains this publish as a side effect. No end-of-step barrier.
    }
}

extern "C" void kernel_launch(void* const* d_in, const int* in_sizes, int n_in,
                              void* d_out, int out_size, void* d_ws, size_t ws_size,
                              hipStream_t stream) {
    (void)in_sizes; (void)n_in; (void)out_size; (void)ws_size;
    const float* x  = (const float*)d_in[0];
    const float* Wf = (const float*)d_in[1];
    const float* bf = (const float*)d_in[2];
    const float* Wi = (const float*)d_in[3];
    const float* bi = (const float*)d_in[4];
    const float* Wo = (const float*)d_in[5];
    const float* bo = (const float*)d_in[6];
    const float* Wc = (const float*)d_in[7];
    const float* bc = (const float*)d_in[8];
    float* out = (float*)d_out;

    // [2][32][256] 8B atoms = 128 KiB; harness poison 0xAAAAAAAA is never a
    // valid tag (tags are 1..2048), so no memset is needed.
    unsigned long long* hatoms = (unsigned long long*)d_ws;

    lstm_kernel<<<NG, BLOCK, 0, stream>>>(x, Wf, bf, Wi, bi, Wo, bo, Wc, bc,
                                          out, hatoms);
}